// Round 1
// 308.859 us; speedup vs baseline: 1.0140x; 1.0140x over previous
//
#include <hip/hip_runtime.h>

typedef unsigned short u16;
typedef __attribute__((ext_vector_type(4))) float floatx4;
typedef __attribute__((ext_vector_type(8))) short short8;

#define MAXROWS 5120   // 4096 slots + 8*128 padding
#define MAXMT 40

__device__ __forceinline__ u16 f2bf(float f) {
    union { float f; unsigned u; } v; v.f = f;
    unsigned r = v.u + 0x7FFF + ((v.u >> 16) & 1);
    return (u16)(r >> 16);
}
__device__ __forceinline__ float bf2f(u16 h) {
    union { unsigned u; float f; } v; v.u = ((unsigned)h) << 16; return v.f;
}
__device__ __forceinline__ float silu_f(float x) { return x / (1.f + __expf(-x)); }

__device__ __forceinline__ void gl_lds16(const void* g, void* l) {
    __builtin_amdgcn_global_load_lds(
        (__attribute__((address_space(1))) unsigned int*)g,
        (__attribute__((address_space(3))) unsigned int*)l, 16, 0, 0);
}

// 8x ds_read_b128 + lgkmcnt(0) fused in one opaque asm block: the compiler's
// waitcnt pass cannot see LDS deps here, so it cannot inject vmcnt(0) drains.
__device__ __forceinline__ void ld_frags(
    unsigned a0, unsigned a1, unsigned a2, unsigned a3,
    unsigned b0, unsigned b1, unsigned b2, unsigned b3,
    short8& af0, short8& af1, short8& af2, short8& af3,
    short8& bf0, short8& bf1, short8& bf2, short8& bf3) {
    asm volatile(
        "ds_read_b128 %0, %8\n\t"
        "ds_read_b128 %1, %9\n\t"
        "ds_read_b128 %2, %10\n\t"
        "ds_read_b128 %3, %11\n\t"
        "ds_read_b128 %4, %12\n\t"
        "ds_read_b128 %5, %13\n\t"
        "ds_read_b128 %6, %14\n\t"
        "ds_read_b128 %7, %15\n\t"
        "s_waitcnt lgkmcnt(0)"
        : "=&v"(af0), "=&v"(af1), "=&v"(af2), "=&v"(af3),
          "=&v"(bf0), "=&v"(bf1), "=&v"(bf2), "=&v"(bf3)
        : "v"(a0), "v"(a1), "v"(a2), "v"(a3),
          "v"(b0), "v"(b1), "v"(b2), "v"(b3));
}

#define WAIT_VM8() __builtin_amdgcn_s_waitcnt(3960)  // vmcnt(8), lgkm/exp no-wait
#define WAIT_VM4() __builtin_amdgcn_s_waitcnt(3956)  // vmcnt(4)
#define WAIT_VM0() __builtin_amdgcn_s_waitcnt(3952)  // vmcnt(0)
#define BAR()      __builtin_amdgcn_s_barrier()

// ---- fused: gate (blocks 0..511) + fp32->bf16 conversion of gemm_A inputs ----
// (W2b/S3b conversion moved into gemm_A's trailing filler blocks — they are
//  only consumed by gemm_B, and gemm_A has 88% of HBM BW idle.)
// S12 layout: 32-row groups: rows g*32+0..15 = sw1[g*16..], g*32+16..31 = sw2[g*16..]
__global__ void conv_gate(const float* __restrict__ w1, const float* __restrict__ w3,
                          const float* __restrict__ sw1, const float* __restrict__ sw2,
                          const float* __restrict__ x, const float* __restrict__ gw,
                          u16* __restrict__ W13, u16* __restrict__ S12,
                          u16* __restrict__ Xb,
                          int* __restrict__ idxA, float* __restrict__ wA) {
    int bid = blockIdx.x;
    if (bid < 512) {  // ---- gate ----
        int w = threadIdx.x >> 6, lane = threadIdx.x & 63;
        int t = bid * 4 + w;
        const float* xr = x + (size_t)t * 1024;
        float acc[8];
#pragma unroll
        for (int e = 0; e < 8; e++) acc[e] = 0.f;
#pragma unroll
        for (int i = 0; i < 16; i++) {
            float xv = xr[lane + (i << 6)];
#pragma unroll
            for (int e = 0; e < 8; e++) acc[e] += xv * gw[e * 1024 + lane + (i << 6)];
        }
#pragma unroll
        for (int e = 0; e < 8; e++)
            for (int off = 32; off > 0; off >>= 1) acc[e] += __shfl_xor(acc[e], off);
        if (lane == 0) {
            float m = acc[0];
#pragma unroll
            for (int e = 1; e < 8; e++) m = fmaxf(m, acc[e]);
            float p[8], s = 0.f;
#pragma unroll
            for (int e = 0; e < 8; e++) { p[e] = __expf(acc[e] - m); s += p[e]; }
            float inv = 1.f / s;
#pragma unroll
            for (int e = 0; e < 8; e++) p[e] *= inv;
            int i0 = 0;
#pragma unroll
            for (int e = 1; e < 8; e++) if (p[e] > p[i0]) i0 = e;
            int i1 = (i0 == 0) ? 1 : 0;
            for (int e = i1 + 1; e < 8; e++) if (e != i0 && p[e] > p[i1]) i1 = e;
            idxA[2 * t] = i0; idxA[2 * t + 1] = i1;
            wA[2 * t] = p[i0]; wA[2 * t + 1] = p[i1];
        }
        return;
    }
    long j = (long)(bid - 512) * 256 + threadIdx.x;
    const float* src; u16* dst; long d;
    if (j < 2097152) {
        long e = j >> 18; src = w1; dst = W13; d = j + (e << 18);
    } else if ((j -= 2097152) < 2097152) {
        long e = j >> 18; src = w3; dst = W13; d = j + (e << 18) + 262144;
    } else if ((j -= 2097152) < 524288) {
        long rr = j >> 8, c4 = j & 255;
        long br = ((rr >> 4) << 5) + (rr & 15);
        src = sw1; dst = S12; d = (br << 8) + c4;
    } else if ((j -= 524288) < 524288) {
        long rr = j >> 8, c4 = j & 255;
        long br = ((rr >> 4) << 5) + 16 + (rr & 15);
        src = sw2; dst = S12; d = (br << 8) + c4;
    } else { j -= 524288; src = x; dst = Xb; d = j; }
    float4 v = ((const float4*)src)[j];
    ushort4 o; o.x = f2bf(v.x); o.y = f2bf(v.y); o.z = f2bf(v.z); o.w = f2bf(v.w);
    ((ushort4*)dst)[d] = o;
}

// ---- single-wave deterministic rank/scatter (0 atomics) ----
__global__ void rank_k(const int* __restrict__ idxA, int* __restrict__ tileexp,
                       int* __restrict__ ntiles, int* __restrict__ slot_of) {
    int lane = threadIdx.x;
    const int* my = idxA + lane * 64;
    int h[8];
#pragma unroll
    for (int e = 0; e < 8; e++) h[e] = 0;
    for (int i = 0; i < 64; i++) {
        int v = my[i];
#pragma unroll
        for (int e = 0; e < 8; e++) h[e] += (v == e);
    }
    int excl[8], tot[8];
#pragma unroll
    for (int e = 0; e < 8; e++) {
        int inc = h[e];
        for (int off = 1; off < 64; off <<= 1) {
            int up = __shfl_up(inc, off);
            if (lane >= off) inc += up;
        }
        excl[e] = inc - h[e];
        tot[e] = __shfl(inc, 63);
    }
    int base[8], tiles = 0;
#pragma unroll
    for (int e = 0; e < 8; e++) {
        base[e] = tiles * 128;
        tiles += (tot[e] + 127) >> 7;
    }
    if (lane == 0) {
        ntiles[0] = tiles;
        int t = 0;
        for (int e = 0; e < 8; e++) {
            int te = (tot[e] + 127) >> 7;
            for (int j = 0; j < te; j++) tileexp[t++] = e;
        }
    }
    int c[8];
#pragma unroll
    for (int e = 0; e < 8; e++) c[e] = base[e] + excl[e];
    for (int i = 0; i < 64; i++) {
        int v = my[i], slot = 0;
#pragma unroll
        for (int e = 0; e < 8; e++) slot += (v == e) ? c[e] : 0;
#pragma unroll
        for (int e = 0; e < 8; e++) c[e] += (v == e);
        slot_of[lane * 64 + i] = slot;
    }
}

__global__ void build_xs(const float* __restrict__ x, const float* __restrict__ wA,
                         const int* __restrict__ slot_of, u16* __restrict__ XS) {
    int s = blockIdx.x, i = threadIdx.x;
    int t = s >> 1; float w = wA[s]; int slot = slot_of[s];
    float4 v = ((const float4*)(x + (size_t)t * 1024))[i];
    ushort4 o; o.x = f2bf(v.x * w); o.y = f2bf(v.y * w); o.z = f2bf(v.z * w); o.w = f2bf(v.w * w);
    ((ushort4*)(XS + (size_t)slot * 1024))[i] = o;
}

// ======== 3-buffer BK=32 core, depth-2 prefetch, raw barriers, vmcnt(8) ========
// LDS u16 layout: A bufs 0/1/2 at [0,4096),[4096,8192),[8192,12288)
//                 B bufs 0/1/2 at [12288,16384),[16384,20480),[20480,24576)
// byte offsets:   A: buf*8192 ; B: 24576 + buf*8192.  Total 48 KB -> 3 blocks/CU.
// Steady state: 2 stages (8 loads) in flight across the barrier; never drain to 0.
#define STAGE32(BUF, Ab, Bb, lda, kk)                                          \
    {                                                                          \
        _Pragma("unroll")                                                      \
        for (int t = 0; t < 2; t++) {                                          \
            int r = (w << 4) + (t << 6) + rloc;                                \
            int cg = clds ^ ((r >> 1) & 3);                                    \
            gl_lds16(Ab + (size_t)(m0 + r) * (lda) + (kk) + (cg << 3),         \
                     LDS + (BUF) * 4096 + ((w << 4) + (t << 6)) * 32);         \
            gl_lds16(Bb + (size_t)(n0 + r) * (lda) + (kk) + (cg << 3),         \
                     LDS + 12288 + (BUF) * 4096 + ((w << 4) + (t << 6)) * 32); \
        }                                                                      \
    }

#define COMPUTE32(BUF)                                                         \
    {                                                                          \
        unsigned bo = (unsigned)(BUF) << 13;                                   \
        short8 af[4], bf[4];                                                   \
        ld_frags(adA[0] + bo, adA[1] + bo, adA[2] + bo, adA[3] + bo,           \
                 adB[0] + bo, adB[1] + bo, adB[2] + bo, adB[3] + bo,           \
                 af[0], af[1], af[2], af[3], bf[0], bf[1], bf[2], bf[3]);      \
        _Pragma("unroll")                                                      \
        for (int i = 0; i < 4; i++)                                            \
            _Pragma("unroll")                                                  \
            for (int j = 0; j < 4; j++)                                        \
                acc[i][j] = __builtin_amdgcn_mfma_f32_16x16x32_bf16(           \
                    af[i], bf[j], acc[i][j], 0, 0, 0);                         \
    }

// NSTEP = number of 32-wide K-steps (K_total/32). Requires NSTEP >= 2.
// step k lives in buffer k%3; stage for step k+2 is issued while computing k.
#define KLOOP3(NSTEP, Ab, Bb, lda, kbeg)                                       \
    {                                                                          \
        STAGE32(0, Ab, Bb, lda, (kbeg));                                       \
        STAGE32(1, Ab, Bb, lda, (kbeg) + 32);                                  \
        int cb = 0, nb = 1, sb = 2;                                            \
        for (int ii = 0; ii + 2 < (NSTEP); ii++) {                             \
            STAGE32(sb, Ab, Bb, lda, (kbeg) + ((ii + 2) << 5));                \
            WAIT_VM8(); BAR();                                                 \
            COMPUTE32(cb);                                                     \
            BAR();                                                             \
            int tt = cb; cb = nb; nb = sb; sb = tt;                            \
        }                                                                      \
        WAIT_VM4(); BAR();                                                     \
        COMPUTE32(cb);                                                         \
        BAR();                                                                 \
        WAIT_VM0(); BAR();                                                     \
        COMPUTE32(nb);                                                         \
    }

#define GEMM_PRE()                                                             \
    int tid = threadIdx.x, w = tid >> 6, lane = tid & 63;                      \
    int wm = w >> 1, wn = w & 1;                                               \
    int rloc = lane >> 2, clds = lane & 3, q = lane >> 4, l15 = lane & 15;     \
    unsigned ldsbase = (unsigned)(size_t)(__attribute__((address_space(3))) u16*)LDS; \
    unsigned adA[4], adB[4];                                                   \
    _Pragma("unroll")                                                          \
    for (int i = 0; i < 4; i++) {                                              \
        int rr = (wm << 6) + (i << 4) + l15;                                   \
        int g = q ^ ((rr >> 1) & 3);                                           \
        adA[i] = ldsbase + rr * 64 + g * 16;                                   \
    }                                                                          \
    _Pragma("unroll")                                                          \
    for (int j = 0; j < 4; j++) {                                              \
        int rr = (wn << 6) + (j << 4) + l15;                                   \
        int g = q ^ ((rr >> 1) & 3);                                           \
        adB[j] = ldsbase + 24576 + rr * 64 + g * 16;                           \
    }                                                                          \
    floatx4 acc[4][4];                                                         \
    _Pragma("unroll")                                                          \
    for (int i = 0; i < 4; i++)                                                \
        _Pragma("unroll")                                                      \
        for (int j = 0; j < 4; j++) {                                          \
            floatx4 z = {0.f, 0.f, 0.f, 0.f}; acc[i][j] = z;                   \
        }

// ---- merged stage-A GEMM, XCD-partitioned; blocks >=1152 convert W2b/S3b ----
__global__ __launch_bounds__(256) void gemm_A(
    const u16* __restrict__ XS, const u16* __restrict__ Xb,
    const u16* __restrict__ W13, const u16* __restrict__ S12,
    const float* __restrict__ b1, const float* __restrict__ b3,
    u16* __restrict__ H, u16* __restrict__ X3h, u16* __restrict__ G,
    const int* __restrict__ tileexp, const int* __restrict__ ntiles,
    const float* __restrict__ w2f, const float* __restrict__ sw3f,
    u16* __restrict__ W2b, u16* __restrict__ S3b) {
    __shared__ u16 LDS[24576];
    int bid = blockIdx.x;
    if (bid >= 1152) {  // ---- filler: convert gemm_B's weights under gemm_A ----
        long j0 = (long)(bid - 1152) * 256 + threadIdx.x;
#pragma unroll
        for (int it = 0; it < 5; it++) {
            long j = j0 + (long)it * 524288;
            const float* src; u16* dst; long d = j;
            if (j < 2097152) { src = w2f; dst = W2b; }
            else             { d = j - 2097152; src = sw3f; dst = S3b; }
            float4 v = ((const float4*)src)[d];
            ushort4 o; o.x = f2bf(v.x); o.y = f2bf(v.y); o.z = f2bf(v.z); o.w = f2bf(v.w);
            ((ushort4*)dst)[d] = o;
        }
        return;
    }
    int xcd = bid & 7, ws = bid >> 3;   // ws in [0,144)
    const u16 *Ab, *Bb; int mt, nt, e = 0; bool routed;
    if (ws < 80) {
        routed = true;
        mt = xcd * 5 + (ws >> 4);
        nt = ws & 15;
        if (mt >= ntiles[0]) return;
        e = tileexp[mt];
        Ab = XS; Bb = W13 + ((size_t)e << 21);
    } else {
        routed = false; int s = ws - 80;
        mt = ((xcd >> 2) << 3) + (s >> 3);
        nt = ((xcd & 3) << 3) + (s & 7);
        Ab = Xb; Bb = S12;
    }
    int m0 = mt * 128, n0 = nt * 128;
    GEMM_PRE();

    KLOOP3(32, Ab, Bb, 1024, 0);

    if (routed) {
#pragma unroll
        for (int i = 0; i < 4; i++) {
            int rowb = m0 + (wm << 6) + (i << 4) + (q << 2);
#pragma unroll
            for (int j = 0; j < 4; j++) {
                int col = n0 + (wn << 6) + (j << 4) + l15;
#pragma unroll
                for (int r = 0; r < 4; r++) {
                    float v = acc[i][j][r];
                    int rw = rowb + r;
                    if (nt < 8) {
                        H[(size_t)rw * 1024 + col] = f2bf(silu_f(v + b1[e * 1024 + col]));
                    } else {
                        int c2 = col - 1024;
                        X3h[(size_t)rw * 1024 + c2] = f2bf(v + b3[e * 1024 + c2]);
                    }
                }
            }
        }
    } else {
#pragma unroll
        for (int i = 0; i < 4; i++) {
            int rowb = m0 + (wm << 6) + (i << 4) + (q << 2);
#pragma unroll
            for (int jp = 0; jp < 4; jp += 2) {
                int brb = n0 + (wn << 6) + (jp << 4);
                int lcol = ((brb >> 5) << 4) + l15;
#pragma unroll
                for (int r = 0; r < 4; r++) {
                    float u = acc[i][jp][r], v = acc[i][jp + 1][r];
                    G[(size_t)(rowb + r) * 2048 + lcol] = f2bf(silu_f(u) * v);
                }
            }
        }
    }
}

// ---- merged stage-B GEMM, split-K=2, XCD-partitioned ----
__global__ __launch_bounds__(256) void gemm_B(
    const u16* __restrict__ H, const u16* __restrict__ G,
    const u16* __restrict__ W2b, const u16* __restrict__ S3b,
    const float* __restrict__ b2, const u16* __restrict__ X3h,
    u16* __restrict__ P0, u16* __restrict__ P1,
    float* __restrict__ Z0, float* __restrict__ Z1,
    const int* __restrict__ tileexp, const int* __restrict__ ntiles) {
    __shared__ u16 LDS[24576];
    int xcd = blockIdx.x & 7, ws = blockIdx.x >> 3;   // ws in [0,112)
    const u16 *Ab, *Bb; int mt, nt, kc, lda, kbeg, nstep, e = 0; bool routed;
    if (ws < 80) {
        routed = true;
        mt = xcd * 5 + (ws >> 4);
        int r = ws & 15; nt = r & 7; kc = r >> 3;
        if (mt >= ntiles[0]) return;
        e = tileexp[mt];
        Ab = H; Bb = W2b + ((size_t)e << 20); lda = 1024; kbeg = kc << 9; nstep = 16;
    } else {
        routed = false; int s = ws - 80;
        kc = s & 1; int s2 = s >> 1;
        mt = ((xcd >> 1) << 2) + (s2 >> 2);
        nt = ((xcd & 1) << 2) + (s2 & 3);
        Ab = G; Bb = S3b; lda = 2048; kbeg = kc << 10; nstep = 32;
    }
    int m0 = mt * 128, n0 = nt * 128;
    GEMM_PRE();

    KLOOP3(nstep, Ab, Bb, lda, kbeg);

    if (routed) {
        u16* Pk = kc ? P1 : P0;
#pragma unroll
        for (int i = 0; i < 4; i++) {
            int rowb = m0 + (wm << 6) + (i << 4) + (q << 2);
#pragma unroll
            for (int j = 0; j < 4; j++) {
                int col = n0 + (wn << 6) + (j << 4) + l15;
#pragma unroll
                for (int r = 0; r < 4; r++) {
                    int rw = rowb + r;
                    float v = acc[i][j][r] + (kc == 0 ? b2[e * 1024 + col] : 0.f);
                    float pv = v * bf2f(X3h[(size_t)rw * 1024 + col]);
                    Pk[(size_t)rw * 1024 + col] = f2bf(pv);
                }
            }
        }
    } else {
        float* Zk = kc ? Z1 : Z0;
#pragma unroll
        for (int i = 0; i < 4; i++) {
            int rowb = m0 + (wm << 6) + (i << 4) + (q << 2);
#pragma unroll
            for (int j = 0; j < 4; j++) {
                int col = n0 + (wn << 6) + (j << 4) + l15;
#pragma unroll
                for (int r = 0; r < 4; r++)
                    Zk[(size_t)(rowb + r) * 1024 + col] = acc[i][j][r];
            }
        }
    }
}

__global__ void final_k(const float* __restrict__ Z0, const float* __restrict__ Z1,
                        const u16* __restrict__ P0, const u16* __restrict__ P1,
                        const int* __restrict__ slot_of, float* __restrict__ out) {
    int i = blockIdx.x * 256 + threadIdx.x;
    int t = i >> 8, c4 = i & 255;
    int s0 = slot_of[2 * t], s1 = slot_of[2 * t + 1];
    float4 z0 = ((const float4*)Z0)[(size_t)t * 256 + c4];
    float4 z1 = ((const float4*)Z1)[(size_t)t * 256 + c4];
    ushort4 a0 = ((const ushort4*)P0)[(size_t)s0 * 256 + c4];
    ushort4 a1 = ((const ushort4*)P1)[(size_t)s0 * 256 + c4];
    ushort4 c0 = ((const ushort4*)P0)[(size_t)s1 * 256 + c4];
    ushort4 c1 = ((const ushort4*)P1)[(size_t)s1 * 256 + c4];
    float4 o;
    o.x = z0.x + z1.x + bf2f(a0.x) + bf2f(a1.x) + bf2f(c0.x) + bf2f(c1.x);
    o.y = z0.y + z1.y + bf2f(a0.y) + bf2f(a1.y) + bf2f(c0.y) + bf2f(c1.y);
    o.z = z0.z + z1.z + bf2f(a0.z) + bf2f(a1.z) + bf2f(c0.z) + bf2f(c1.z);
    o.w = z0.w + z1.w + bf2f(a0.w) + bf2f(a1.w) + bf2f(c0.w) + bf2f(c1.w);
    ((float4*)out)[(size_t)t * 256 + c4] = o;
}

extern "C" void kernel_launch(void* const* d_in, const int* in_sizes, int n_in,
                              void* d_out, int out_size, void* d_ws, size_t ws_size,
                              hipStream_t stream) {
    const float* x   = (const float*)d_in[0];
    const float* gw  = (const float*)d_in[1];
    const float* w1  = (const float*)d_in[2];
    const float* b1  = (const float*)d_in[3];
    const float* w2  = (const float*)d_in[4];
    const float* b2  = (const float*)d_in[5];
    const float* w3  = (const float*)d_in[6];
    const float* b3  = (const float*)d_in[7];
    const float* sw1 = (const float*)d_in[8];
    const float* sw2 = (const float*)d_in[9];
    const float* sw3 = (const float*)d_in[10];
    float* out = (float*)d_out;

    char* p = (char*)d_ws;
    int* ntiles  = (int*)(p + 192);
    int* tileexp = (int*)(p + 256);
    size_t off = 4096;
    u16*   XS      = (u16*)(p + off);   off += (size_t)MAXROWS * 1024 * 2;
    int*   idxA    = (int*)(p + off);   off += 16384;
    float* wA      = (float*)(p + off); off += 16384;
    int*   slot_of = (int*)(p + off);   off += 16384;
    u16*   H       = (u16*)(p + off);   off += (size_t)MAXROWS * 1024 * 2;
    u16*   X3h     = (u16*)(p + off);   off += (size_t)MAXROWS * 1024 * 2;
    u16*   P0      = (u16*)(p + off);   off += (size_t)MAXROWS * 1024 * 2;
    u16*   P1      = (u16*)(p + off);   off += (size_t)MAXROWS * 1024 * 2;
    float* Z0      = (float*)(p + off); off += (size_t)2048 * 1024 * 4;
    float* Z1      = (float*)(p + off); off += (size_t)2048 * 1024 * 4;
    u16*   W13     = (u16*)(p + off);   off += (size_t)8 * 2048 * 1024 * 2;
    u16*   W2b     = (u16*)(p + off);   off += (size_t)8 * 1024 * 1024 * 2;
    u16*   S12     = (u16*)(p + off);   off += (size_t)4096 * 1024 * 2;
    u16*   S3b     = (u16*)(p + off);   off += (size_t)1024 * 2048 * 2;
    u16*   Xb      = (u16*)(p + off);   off += (size_t)2048 * 1024 * 2;
    u16*   G       = (u16*)(p + off);   off += (size_t)2048 * 2048 * 2;

    // gate + conversions needed by gemm_A only: 512 + 5767168/256 = 23040 blocks
    conv_gate<<<23040, 256, 0, stream>>>(w1, w3, sw1, sw2, x, gw,
                                         W13, S12, Xb, idxA, wA);
    rank_k<<<1, 64, 0, stream>>>(idxA, tileexp, ntiles, slot_of);
    build_xs<<<4096, 256, 0, stream>>>(x, wA, slot_of, XS);

    // 1152 GEMM blocks + 2048 conversion-filler blocks (W2b/S3b for gemm_B)
    gemm_A<<<3200, 256, 0, stream>>>(XS, Xb, W13, S12, b1, b3, H, X3h, G,
                                     tileexp, ntiles, w2, sw3, W2b, S3b);
    gemm_B<<<896, 256, 0, stream>>>(H, G, W2b, S3b, b2, X3h, P0, P1, Z0, Z1,
                                    tileexp, ntiles);
    final_k<<<2048, 256, 0, stream>>>(Z0, Z1, P0, P1, slot_of, out);
}